// Round 20
// baseline (94.571 us; speedup 1.0000x reference)
//
#include <hip/hip_runtime.h>

typedef unsigned short u16;
typedef __attribute__((ext_vector_type(8))) short short8;
typedef __attribute__((ext_vector_type(4))) float f32x4;
typedef __attribute__((ext_vector_type(2))) unsigned uint2v;

// ---------- helpers ----------
__device__ __forceinline__ u16 f2bf(float f) {
  union { float f; unsigned u; } v; v.f = f;
  unsigned r = v.u + 0x7FFFu + ((v.u >> 16) & 1u);
  return (u16)(r >> 16);
}
__device__ __forceinline__ float bf2f(u16 u) {
  union { unsigned u; float f; } v; v.u = ((unsigned)u) << 16;
  return v.f;
}
__device__ __forceinline__ void gload_lds16(const u16* g, u16* l) {
  __builtin_amdgcn_global_load_lds((const __attribute__((address_space(1))) void*)g,
                                   (__attribute__((address_space(3))) void*)l,
                                   16, 0, 0);
}
__device__ __forceinline__ void gload_lds16f(const float* g, u16* l) {
  __builtin_amdgcn_global_load_lds((const __attribute__((address_space(1))) void*)g,
                                   (__attribute__((address_space(3))) void*)l,
                                   16, 0, 0);
}

#if __has_builtin(__builtin_amdgcn_exp2f)
#define EXP2(x) __builtin_amdgcn_exp2f(x)
#else
#define EXP2(x) exp2f(x)
#endif

// ---------- constants ----------
#define BATCH 8
#define SEQ   1024
#define DIM   512
#define NH    8
#define DH    64
#define MROWS (BATCH * SEQ)   // 8192

// ---------- f32 -> bf16 convert for the 4 weight matrices only ----------
__global__ void cvt_w(const float* __restrict__ Wq, const float* __restrict__ Wk,
                      const float* __restrict__ Wv, const float* __restrict__ Wo,
                      u16* __restrict__ out) {
  const float* s = (blockIdx.y == 0) ? Wq : (blockIdx.y == 1) ? Wk
                   : (blockIdx.y == 2) ? Wv : Wo;
  const float4* src = (const float4*)s;
  u16* dst = out + (size_t)blockIdx.y * (DIM * DIM);
  int i = blockIdx.x * 256 + threadIdx.x;
  float4 v = src[i];
  ushort4 r;
  r.x = f2bf(v.x); r.y = f2bf(v.y); r.z = f2bf(v.z); r.w = f2bf(v.w);
  *(ushort4*)&dst[i * 4] = r;
}

// ---------- projections: 64-row blocks (ffn-proven granularity), f32 A via
// global_load_lds with XOR-swizzled SOURCE chunk (linear LDS dest), bf16
// conversion on the READ path. grid (m=128, n=4, z=3) m-fastest: same-A
// blocks spaced 128 == 0 mod 8 -> same XCD. 32 KB LDS -> 4 blocks/CU. ----------
__global__ __launch_bounds__(256, 4) void proj_gemm(
    const float* __restrict__ Qf, const float* __restrict__ Kf,
    const u16* __restrict__ Wbf,
    const float* __restrict__ bq, const float* __restrict__ bk,
    const float* __restrict__ bv,
    u16* __restrict__ Qp, u16* __restrict__ Kp, u16* __restrict__ VpT) {
  __shared__ alignas(16) u16 ldsA[2 * 4096];   // 2 x 8 KB f32 A tiles (64x32)
  __shared__ alignas(16) u16 ldsB[2 * 4096];   // 2 x 8 KB bf16 W tiles (128x32)

  const int tid = threadIdx.x;
  const int z = blockIdx.z;
  const int m0 = blockIdx.x * 64;
  const int n0 = blockIdx.y * 128;

  const float* A32 = (z == 0) ? Qf : Kf;
  const u16* W = Wbf + (size_t)z * (DIM * DIM);
  const float* bias = (z == 0) ? bq : (z == 1) ? bk : bv;

  const int lane = tid & 63;
  const int wv = tid >> 6;
  const int wr = wv >> 1, wc = wv & 1;
  const int lr = lane & 15, lg = lane >> 4;
  const int wbase = tid & 192;

  // A source: slot tid -> row tid>>3, swizzled chunk (tid&7)^((tid>>3)&7).
  // Second slot (tid+256) is row+32 (32 == 0 mod 8: same swizzle mask works).
  const int schunk = (tid & 7) ^ ((tid >> 3) & 7);
  const float* abase = A32 + (size_t)(m0 + (tid >> 3)) * DIM + schunk * 4;

#define PSTAGE_A(buf, kt)                                                       \
  {                                                                             \
    _Pragma("unroll")                                                           \
    for (int i = 0; i < 2; ++i) {                                               \
      gload_lds16f(abase + (size_t)(i * 32) * DIM + (kt) * 32,                  \
                   ldsA + (buf) * 4096 + (i * 256 + wbase) * 8);                \
    }                                                                           \
  }

#define PSTAGE_B(buf, kt)                                                       \
  {                                                                             \
    _Pragma("unroll")                                                           \
    for (int i = 0; i < 2; ++i) {                                               \
      const int T = i * 256 + tid;                                              \
      const int row = T & 127, kc = T >> 7;                                     \
      gload_lds16(W + (size_t)(n0 + row) * DIM + (kt) * 32 + kc * 8,            \
                  ldsB + (buf) * 4096 + (i * 256 + wbase) * 8);                 \
    }                                                                           \
  }

  // read offsets (u16 units): row R = wr*32 + m*16 + lr; chunks 2lg, 2lg+1
  // at physical chunk ^(R&7); row stride 64 elems, m stride 16*64.
  const int xr = lr & 7;
  const int aoff0 = (wr * 32 + lr) * 64 + (((2 * lg) ^ xr) * 8);
  const int aoff1 = (wr * 32 + lr) * 64 + (((2 * lg + 1) ^ xr) * 8);

  f32x4 acc[2][4] = {};

  PSTAGE_A(0, 0);
  PSTAGE_B(0, 0);
  __syncthreads();

  int cur = 0;
#pragma unroll 1
  for (int kt = 0; kt < 16; ++kt) {
    if (kt < 15) { PSTAGE_A(cur ^ 1, kt + 1); PSTAGE_B(cur ^ 1, kt + 1); }

    short8 av[2], bw[4];
#pragma unroll
    for (int m = 0; m < 2; ++m) {
      f32x4 a0 = *(const f32x4*)(ldsA + cur * 4096 + aoff0 + m * 1024);
      f32x4 a1 = *(const f32x4*)(ldsA + cur * 4096 + aoff1 + m * 1024);
      unsigned u0, u1, u2, u3;
      asm("v_cvt_pk_bf16_f32 %0, %1, %2" : "=v"(u0) : "v"(a0[0]), "v"(a0[1]));
      asm("v_cvt_pk_bf16_f32 %0, %1, %2" : "=v"(u1) : "v"(a0[2]), "v"(a0[3]));
      asm("v_cvt_pk_bf16_f32 %0, %1, %2" : "=v"(u2) : "v"(a1[0]), "v"(a1[1]));
      asm("v_cvt_pk_bf16_f32 %0, %1, %2" : "=v"(u3) : "v"(a1[2]), "v"(a1[3]));
      union { unsigned u[4]; short8 s; } pk_;
      pk_.u[0] = u0; pk_.u[1] = u1; pk_.u[2] = u2; pk_.u[3] = u3;
      av[m] = pk_.s;
    }
#pragma unroll
    for (int n = 0; n < 4; ++n)
      bw[n] = *(const short8*)(ldsB + cur * 4096 + (lg * 128 + wc * 64 + n * 16 + lr) * 8);
#pragma unroll
    for (int m = 0; m < 2; ++m)
#pragma unroll
      for (int n = 0; n < 4; ++n)
        acc[m][n] = __builtin_amdgcn_mfma_f32_16x16x32_bf16(av[m], bw[n], acc[m][n], 0, 0, 0);
    __syncthreads();
    cur ^= 1;
  }
#undef PSTAGE_A
#undef PSTAGE_B

  float bn[4];
#pragma unroll
  for (int n = 0; n < 4; ++n) bn[n] = bias[n0 + wc * 64 + n * 16 + lr];

  if (z < 2) {
    u16* outp = (z == 0) ? Qp : Kp;
#pragma unroll
    for (int m = 0; m < 2; ++m)
#pragma unroll
      for (int n = 0; n < 4; ++n)
#pragma unroll
        for (int r = 0; r < 4; ++r) {
          const int row = m0 + wr * 32 + m * 16 + lg * 4 + r;
          const int col = n0 + wc * 64 + n * 16 + lr;
          outp[(size_t)row * DIM + col] = f2bf(acc[m][n][r] + bn[n]);
        }
  } else {
#pragma unroll
    for (int m = 0; m < 2; ++m)
#pragma unroll
      for (int n = 0; n < 4; ++n) {
        const int grow = m0 + wr * 32 + m * 16 + lg * 4;
        const int b = grow >> 10;
        const int s = grow & 1023;
        const int col = n0 + wc * 64 + n * 16 + lr;
        ushort4 pk;
        pk.x = f2bf(acc[m][n][0] + bn[n]);
        pk.y = f2bf(acc[m][n][1] + bn[n]);
        pk.z = f2bf(acc[m][n][2] + bn[n]);
        pk.w = f2bf(acc[m][n][3] + bn[n]);
        *(ushort4*)&VpT[(size_t)b * (DIM * SEQ) + (size_t)col * SEQ + s] = pk;
      }
  }
}

// ---------- flash attention: 8 waves, QBLK=128, KVBLK=64, XCD-local grid.
// K/V LDS row-XOR swizzle (pre-swizzled global source row, linear LDS dest).
// Row-sum l computed on the MFMA pipe via an all-ones B fragment.
__global__ __launch_bounds__(512, 4) void attn_kernel(
    const u16* __restrict__ Qp, const u16* __restrict__ Kp,
    const u16* __restrict__ VpT, u16* __restrict__ Opre) {
  __shared__ alignas(16) u16 klds[2][4096];     // [dc8][ks64][8], row-swizzled
  __shared__ alignas(16) u16 vlds[2][4096];     // [kc8][d64][8], row-swizzled
  __shared__ alignas(16) u16 plds[8][64 * 16];  // per-wave P^T [ks64][q16]

  const int tid = threadIdx.x;
  const int lane = tid & 63, wv = tid >> 6;   // 8 waves
  const int lr = lane & 15, lg = lane >> 4;
  const int q0 = blockIdx.y * 128;            // wave wv owns rows q0+wv*16..+15
  const int b = blockIdx.x >> 3, h = blockIdx.x & 7;
  const size_t rowbase = (size_t)b * SEQ;
  const int hoff = h * DH;

  // Q fragments for this wave's 16 q-rows, pre-scaled by 1/sqrt(512)*log2(e)
  const float csc = 0.063762f;
  short8 aq[2];
#pragma unroll
  for (int t = 0; t < 2; ++t) {
    short8 raw = *(const short8*)(Qp + (rowbase + q0 + wv * 16 + lr) * DIM +
                                  hoff + t * 32 + lg * 8);
    short8 s;
#pragma unroll
    for (int j = 0; j < 8; ++j) s[j] = (short)f2bf(bf2f((u16)raw[j]) * csc);
    aq[t] = s;
  }

  // all-ones bf16 B fragment for the row-sum MFMA
  short8 ones;
#pragma unroll
  for (int j = 0; j < 8; ++j) ones[j] = (short)0x3F80;

#define STAGEKV(buf, kt)                                                        \
  {                                                                             \
    const int ks0_ = (kt) * 64;                                                 \
    const int rr = tid & 63, cc = tid >> 6;                                     \
    const int srr = rr ^ (cc << 1);                                             \
    gload_lds16(Kp + (rowbase + ks0_ + srr) * DIM + hoff + cc * 8,              \
                &klds[buf][tid * 8]);                                           \
    gload_lds16(VpT + (size_t)b * (DIM * SEQ) + (size_t)(hoff + srr) * SEQ +    \
                    ks0_ + cc * 8,                                              \
                &vlds[buf][tid * 8]);                                           \
  }

  const int kx0 = lr ^ (lg << 1);

  u16* pw = &plds[wv][0];
  unsigned pbase = (unsigned)(uintptr_t)(__attribute__((address_space(3))) u16*)pw;
  const unsigned ta00 = pbase + (unsigned)lg * 128u;
  const unsigned ta01 = ta00 + 128u;
  const unsigned ta10 = ta00 + 1024u;
  const unsigned ta11 = ta00 + 1152u;

  f32x4 l_acc = {};
  f32x4 o_acc[4] = {};

  STAGEKV(0, 0);
  __syncthreads();

  int cur = 0;
#pragma unroll 1
  for (int kt = 0; kt < 16; ++kt) {
    if (kt < 15) STAGEKV(cur ^ 1, kt + 1);

    // ---- QK^T from LDS K (swizzled row read) ----
    f32x4 sa[4] = {};
    __builtin_amdgcn_s_setprio(1);
#pragma unroll
    for (int t = 0; t < 2; ++t) {
      const int kxt = kx0 ^ (t << 3);
#pragma unroll
      for (int f = 0; f < 4; ++f) {
        short8 bk_ = *(const short8*)(&klds[cur][((lg + 4 * t) * 64 + f * 16 + kxt) * 8]);
        sa[f] = __builtin_amdgcn_mfma_f32_16x16x32_bf16(aq[t], bk_, sa[f], 0, 0, 0);
      }
    }
    __builtin_amdgcn_s_setprio(0);

    // ---- V fragments issued early (swizzled row read) ----
    short8 bvf[8];
#pragma unroll
    for (int n = 0; n < 4; ++n)
#pragma unroll
      for (int t = 0; t < 2; ++t) {
        const int kxt = kx0 ^ (t << 3);
        bvf[n * 2 + t] = *(const short8*)(&vlds[cur][((lg + 4 * t) * 64 + n * 16 + kxt) * 8]);
      }

    // ---- p = 2^sa ; pack to P^T [ks64][16q] in per-wave LDS ----
#pragma unroll
    for (int f = 0; f < 4; ++f) {
      float p0 = EXP2(sa[f][0]);
      float p1 = EXP2(sa[f][1]);
      float p2 = EXP2(sa[f][2]);
      float p3 = EXP2(sa[f][3]);
      unsigned lo, hi;
      asm("v_cvt_pk_bf16_f32 %0, %1, %2" : "=v"(lo) : "v"(p0), "v"(p1));
      asm("v_cvt_pk_bf16_f32 %0, %1, %2" : "=v"(hi) : "v"(p2), "v"(p3));
      uint2v pk; pk.x = lo; pk.y = hi;
      *(uint2v*)&pw[(f * 16 + lr) * 16 + lg * 4] = pk;
    }

    // ---- wave-local fence, hardware transpose-read P as A-fragments ----
    asm volatile("s_waitcnt lgkmcnt(0)" ::: "memory");
    uint2v t00, t01, t10, t11;
    asm volatile("ds_read_b64_tr_b16 %0, %1" : "=v"(t00) : "v"(ta00));
    asm volatile("ds_read_b64_tr_b16 %0, %1" : "=v"(t01) : "v"(ta01));
    asm volatile("ds_read_b64_tr_b16 %0, %1" : "=v"(t10) : "v"(ta10));
    asm volatile("ds_read_b64_tr_b16 %0, %1" : "=v"(t11) : "v"(ta11));
    asm volatile("s_waitcnt lgkmcnt(0)" ::: "memory");
    __builtin_amdgcn_sched_barrier(0);

    short8 ap[2];
    {
      union { unsigned u[4]; short8 s; } u0, u1;
      u0.u[0] = t00.x; u0.u[1] = t00.y; u0.u[2] = t01.x; u0.u[3] = t01.y;
      u1.u[0] = t10.x; u1.u[1] = t10.y; u1.u[2] = t11.x; u1.u[3] = t11.y;
      ap[0] = u0.s; ap[1] = u1.s;
    }

    // ---- PV + row-sum (ones-MFMA) ----
    __builtin_amdgcn_s_setprio(1);
#pragma unroll
    for (int n = 0; n < 4; ++n)
#pragma unroll
      for (int t = 0; t < 2; ++t)
        o_acc[n] = __builtin_amdgcn_mfma_f32_16x16x32_bf16(ap[t], bvf[n * 2 + t], o_acc[n], 0, 0, 0);
    l_acc = __builtin_amdgcn_mfma_f32_16x16x32_bf16(ap[0], ones, l_acc, 0, 0, 0);
    l_acc = __builtin_amdgcn_mfma_f32_16x16x32_bf16(ap[1], ones, l_acc, 0, 0, 0);
    __builtin_amdgcn_s_setprio(0);

    __syncthreads();
    cur ^= 1;
  }
#undef STAGEKV

  // ---- epilogue: divide by row sum (already per-lane), add Q residual ----
  float inv[4];
#pragma unroll
  for (int r = 0; r < 4; ++r) inv[r] = 1.0f / l_acc[r];
#pragma unroll
  for (int n = 0; n < 4; ++n)
#pragma unroll
    for (int r = 0; r < 4; ++r) {
      const size_t row = rowbase + q0 + wv * 16 + lg * 4 + r;
      const int col = hoff + n * 16 + lr;
      const float ctx = o_acc[n][r] * inv[r];
      const float qv = bf2f(Qp[row * DIM + col]);
      Opre[row * DIM + col] = f2bf(qv + ctx);
    }
}

// ---------- FFN: out = Opre + relu(Opre @ Wo^T + bo), f32 output ----------
// 64-row blocks: grid (128,4) = 512 blocks -> ALL 256 CUs active.
__global__ __launch_bounds__(256, 4) void ffn_gemm(
    const u16* __restrict__ Opre, const u16* __restrict__ Wo_bf,
    const float* __restrict__ bo, float* __restrict__ out) {
  __shared__ alignas(16) u16 ldsA[2 * 2048];   // 2 x 4 KB: A 64x32 bf16
  __shared__ alignas(16) u16 ldsB[2 * 4096];   // 2 x 8 KB: B 128x32 bf16

  const int tid = threadIdx.x;
  const int m0 = blockIdx.x * 64;
  const int n0 = blockIdx.y * 128;

  const int lane = tid & 63;
  const int wv = tid >> 6;
  const int wr = wv >> 1, wc = wv & 1;
  const int lr = lane & 15, lg = lane >> 4;
  const int wbase = tid & 192;

#define FSTAGE(buf, kt)                                                         \
  {                                                                             \
    const int rr = tid & 63, cc = tid >> 6;                                     \
    gload_lds16(Opre + (size_t)(m0 + rr) * DIM + (kt) * 32 + cc * 8,            \
                ldsA + (buf) * 2048 + tid * 8);                                 \
    _Pragma("unroll")                                                           \
    for (int i = 0; i < 2; ++i) {                                               \
      const int T = i * 256 + tid;                                              \
      const int row = T & 127, kc = T >> 7;                                     \
      gload_lds16(Wo_bf + (size_t)(n0 + row) * DIM + (kt) * 32 + kc * 8,        \
                  ldsB + (buf) * 4096 + (i * 256 + wbase) * 8);                 \
    }                                                                           \
  }

  f32x4 acc[2][4] = {};

  FSTAGE(0, 0);
  __syncthreads();

  int cur = 0;
#pragma unroll 1
  for (int kt = 0; kt < 16; ++kt) {
    if (kt < 15) FSTAGE(cur ^ 1, kt + 1);
    short8 av[2], bw[4];
#pragma unroll
    for (int m = 0; m < 2; ++m)
      av[m] = *(const short8*)(ldsA + cur * 2048 + (lg * 64 + wr * 32 + m * 16 + lr) * 8);
#pragma unroll
    for (int n = 0; n < 4; ++n)
      bw[n] = *(const short8*)(ldsB + cur * 4096 + (lg * 128 + wc * 64 + n * 16 + lr) * 8);
#pragma unroll
    for (int m = 0; m < 2; ++m)
#pragma unroll
      for (int n = 0; n < 4; ++n)
        acc[m][n] = __builtin_amdgcn_mfma_f32_16x16x32_bf16(av[m], bw[n], acc[m][n], 0, 0, 0);
    __syncthreads();
    cur ^= 1;
  }
#undef FSTAGE

  float bn[4];
#pragma unroll
  for (int n = 0; n < 4; ++n) bn[n] = bo[n0 + wc * 64 + n * 16 + lr];

#pragma unroll
  for (int m = 0; m < 2; ++m)
#pragma unroll
    for (int n = 0; n < 4; ++n)
#pragma unroll
      for (int r = 0; r < 4; ++r) {
        const int row = m0 + wr * 32 + m * 16 + lg * 4 + r;
        const int col = n0 + wc * 64 + n * 16 + lr;
        const float v = acc[m][n][r] + bn[n];
        const float o = bf2f(Opre[(size_t)row * DIM + col]);
        out[(size_t)row * DIM + col] = o + fmaxf(v, 0.f);
      }
}

// ---------- launch ----------
extern "C" void kernel_launch(void* const* d_in, const int* in_sizes, int n_in,
                              void* d_out, int out_size, void* d_ws, size_t ws_size,
                              hipStream_t stream) {
  const float* Q  = (const float*)d_in[0];
  const float* K  = (const float*)d_in[1];
  const float* Wq = (const float*)d_in[2];
  const float* bq = (const float*)d_in[3];
  const float* Wk = (const float*)d_in[4];
  const float* bk = (const float*)d_in[5];
  const float* Wv = (const float*)d_in[6];
  const float* bv = (const float*)d_in[7];
  const float* Wo = (const float*)d_in[8];
  const float* bo = (const float*)d_in[9];

  char* ws = (char*)d_ws;
  const size_t SZ = (size_t)MROWS * DIM * sizeof(u16);       // 8 MiB per bf16 tensor
  const size_t WSZ = 4 * (size_t)(DIM * DIM) * sizeof(u16);  // 2 MiB weights
  u16* Wbf  = (u16*)(ws + 0);
  u16* Qp   = (u16*)(ws + WSZ);
  u16* Kp   = (u16*)((char*)Qp + SZ);
  u16* VpT  = (u16*)((char*)Kp + SZ);
  u16* Opre = (u16*)((char*)VpT + SZ);

  cvt_w<<<dim3(256, 4), 256, 0, stream>>>(Wq, Wk, Wv, Wo, Wbf);
  proj_gemm<<<dim3(128, 4, 3), 256, 0, stream>>>(Q, K, Wbf, bq, bk, bv, Qp, Kp, VpT);
  attn_kernel<<<dim3(64, 8), 512, 0, stream>>>(Qp, Kp, VpT, Opre);
  ffn_gemm<<<dim3(128, 4), 256, 0, stream>>>(Opre, Wbf + 3 * (DIM * DIM), bo, (float*)d_out);
}

// Round 21
// 80.698 us; speedup vs baseline: 1.1719x; 1.1719x over previous
//
#include <hip/hip_runtime.h>

typedef unsigned short u16;
typedef __attribute__((ext_vector_type(8))) short short8;
typedef __attribute__((ext_vector_type(4))) float f32x4;
typedef __attribute__((ext_vector_type(2))) unsigned uint2v;

// ---------- helpers ----------
__device__ __forceinline__ u16 f2bf(float f) {
  union { float f; unsigned u; } v; v.f = f;
  unsigned r = v.u + 0x7FFFu + ((v.u >> 16) & 1u);
  return (u16)(r >> 16);
}
__device__ __forceinline__ float bf2f(u16 u) {
  union { unsigned u; float f; } v; v.u = ((unsigned)u) << 16;
  return v.f;
}
__device__ __forceinline__ void gload_lds16(const u16* g, u16* l) {
  __builtin_amdgcn_global_load_lds((const __attribute__((address_space(1))) void*)g,
                                   (__attribute__((address_space(3))) void*)l,
                                   16, 0, 0);
}
__device__ __forceinline__ void gload_lds16f(const float* g, u16* l) {
  __builtin_amdgcn_global_load_lds((const __attribute__((address_space(1))) void*)g,
                                   (__attribute__((address_space(3))) void*)l,
                                   16, 0, 0);
}

#if __has_builtin(__builtin_amdgcn_exp2f)
#define EXP2(x) __builtin_amdgcn_exp2f(x)
#else
#define EXP2(x) exp2f(x)
#endif

// ---------- constants ----------
#define BATCH 8
#define SEQ   1024
#define DIM   512
#define NH    8
#define DH    64
#define MROWS (BATCH * SEQ)   // 8192

// ---------- f32 -> bf16 convert for the 4 weight matrices only ----------
__global__ void cvt_w(const float* __restrict__ Wq, const float* __restrict__ Wk,
                      const float* __restrict__ Wv, const float* __restrict__ Wo,
                      u16* __restrict__ out) {
  const float* s = (blockIdx.y == 0) ? Wq : (blockIdx.y == 1) ? Wk
                   : (blockIdx.y == 2) ? Wv : Wo;
  const float4* src = (const float4*)s;
  u16* dst = out + (size_t)blockIdx.y * (DIM * DIM);
  int i = blockIdx.x * 256 + threadIdx.x;
  float4 v = src[i];
  ushort4 r;
  r.x = f2bf(v.x); r.y = f2bf(v.y); r.z = f2bf(v.z); r.w = f2bf(v.w);
  *(ushort4*)&dst[i * 4] = r;
}

// ---------- projections: 128-row blocks, f32 A staged via global_load_lds
// with XOR-swizzled SOURCE chunk (linear LDS dest), bf16 conversion on the
// READ path. grid (m=64, n=4, z=3) m-fastest: same-A blocks spaced 64 == 0
// mod 8 -> same XCD. 48 KB LDS -> 3 blocks/CU. (Proven best: rounds 13/16/19;
// 64-row retile regressed via L2 working-set + barrier amortization.) ----------
__global__ __launch_bounds__(256, 3) void proj_gemm(
    const float* __restrict__ Qf, const float* __restrict__ Kf,
    const u16* __restrict__ Wbf,
    const float* __restrict__ bq, const float* __restrict__ bk,
    const float* __restrict__ bv,
    u16* __restrict__ Qp, u16* __restrict__ Kp, u16* __restrict__ VpT) {
  __shared__ alignas(16) u16 ldsA[2 * 8192];   // 2 x 16 KB f32 A tiles
  __shared__ alignas(16) u16 ldsB[2 * 4096];   // 2 x 8 KB bf16 W tiles

  const int tid = threadIdx.x;
  const int z = blockIdx.z;
  const int m0 = blockIdx.x * 128;
  const int n0 = blockIdx.y * 128;

  const float* A32 = (z == 0) ? Qf : Kf;
  const u16* W = Wbf + (size_t)z * (DIM * DIM);
  const float* bias = (z == 0) ? bq : (z == 1) ? bk : bv;

  const int lane = tid & 63;
  const int wv = tid >> 6;
  const int wr = wv >> 1, wc = wv & 1;
  const int lr = lane & 15, lg = lane >> 4;
  const int wbase = tid & 192;

  const int schunk = (tid & 7) ^ ((tid >> 3) & 7);          // swizzled source chunk
  const float* abase = A32 + (size_t)(m0 + (tid >> 3)) * DIM + schunk * 4;

#define PSTAGE_A(buf, kt)                                                       \
  {                                                                             \
    _Pragma("unroll")                                                           \
    for (int i = 0; i < 4; ++i) {                                               \
      gload_lds16f(abase + (size_t)(i * 32) * DIM + (kt) * 32,                  \
                   ldsA + (buf) * 8192 + (i * 256 + wbase) * 8);                \
    }                                                                           \
  }

#define PSTAGE_B(buf, kt)                                                       \
  {                                                                             \
    _Pragma("unroll")                                                           \
    for (int i = 0; i < 2; ++i) {                                               \
      const int T = i * 256 + tid;                                              \
      const int row = T & 127, kc = T >> 7;                                     \
      gload_lds16(W + (size_t)(n0 + row) * DIM + (kt) * 32 + kc * 8,            \
                  ldsB + (buf) * 4096 + (i * 256 + wbase) * 8);                 \
    }                                                                           \
  }

  const int xr = lr & 7;
  const int aoff0 = (wr * 64 + lr) * 64 + (((2 * lg) ^ xr) * 8);
  const int aoff1 = (wr * 64 + lr) * 64 + (((2 * lg + 1) ^ xr) * 8);

  f32x4 acc[4][4] = {};

  PSTAGE_A(0, 0);
  PSTAGE_B(0, 0);
  __syncthreads();

  int cur = 0;
#pragma unroll 1
  for (int kt = 0; kt < 16; ++kt) {
    if (kt < 15) { PSTAGE_A(cur ^ 1, kt + 1); PSTAGE_B(cur ^ 1, kt + 1); }

    short8 av[4], bw[4];
#pragma unroll
    for (int m = 0; m < 4; ++m) {
      f32x4 a0 = *(const f32x4*)(ldsA + cur * 8192 + aoff0 + m * 16 * 64);
      f32x4 a1 = *(const f32x4*)(ldsA + cur * 8192 + aoff1 + m * 16 * 64);
      unsigned u0, u1, u2, u3;
      asm("v_cvt_pk_bf16_f32 %0, %1, %2" : "=v"(u0) : "v"(a0[0]), "v"(a0[1]));
      asm("v_cvt_pk_bf16_f32 %0, %1, %2" : "=v"(u1) : "v"(a0[2]), "v"(a0[3]));
      asm("v_cvt_pk_bf16_f32 %0, %1, %2" : "=v"(u2) : "v"(a1[0]), "v"(a1[1]));
      asm("v_cvt_pk_bf16_f32 %0, %1, %2" : "=v"(u3) : "v"(a1[2]), "v"(a1[3]));
      union { unsigned u[4]; short8 s; } pk_;
      pk_.u[0] = u0; pk_.u[1] = u1; pk_.u[2] = u2; pk_.u[3] = u3;
      av[m] = pk_.s;
    }
#pragma unroll
    for (int n = 0; n < 4; ++n)
      bw[n] = *(const short8*)(ldsB + cur * 4096 + (lg * 128 + wc * 64 + n * 16 + lr) * 8);
#pragma unroll
    for (int m = 0; m < 4; ++m)
#pragma unroll
      for (int n = 0; n < 4; ++n)
        acc[m][n] = __builtin_amdgcn_mfma_f32_16x16x32_bf16(av[m], bw[n], acc[m][n], 0, 0, 0);
    __syncthreads();
    cur ^= 1;
  }
#undef PSTAGE_A
#undef PSTAGE_B

  float bn[4];
#pragma unroll
  for (int n = 0; n < 4; ++n) bn[n] = bias[n0 + wc * 64 + n * 16 + lr];

  if (z < 2) {
    u16* outp = (z == 0) ? Qp : Kp;
#pragma unroll
    for (int m = 0; m < 4; ++m)
#pragma unroll
      for (int n = 0; n < 4; ++n)
#pragma unroll
        for (int r = 0; r < 4; ++r) {
          const int row = m0 + wr * 64 + m * 16 + lg * 4 + r;
          const int col = n0 + wc * 64 + n * 16 + lr;
          outp[(size_t)row * DIM + col] = f2bf(acc[m][n][r] + bn[n]);
        }
  } else {
#pragma unroll
    for (int m = 0; m < 4; ++m)
#pragma unroll
      for (int n = 0; n < 4; ++n) {
        const int grow = m0 + wr * 64 + m * 16 + lg * 4;
        const int b = grow >> 10;
        const int s = grow & 1023;
        const int col = n0 + wc * 64 + n * 16 + lr;
        ushort4 pk;
        pk.x = f2bf(acc[m][n][0] + bn[n]);
        pk.y = f2bf(acc[m][n][1] + bn[n]);
        pk.z = f2bf(acc[m][n][2] + bn[n]);
        pk.w = f2bf(acc[m][n][3] + bn[n]);
        *(ushort4*)&VpT[(size_t)b * (DIM * SEQ) + (size_t)col * SEQ + s] = pk;
      }
  }
}

// ---------- flash attention: 8 waves, QBLK=128, KVBLK=64, XCD-local grid.
// K/V LDS row-XOR swizzle (pre-swizzled global source row, linear LDS dest).
// Row-sum l computed on the MFMA pipe via an all-ones B fragment.
__global__ __launch_bounds__(512, 4) void attn_kernel(
    const u16* __restrict__ Qp, const u16* __restrict__ Kp,
    const u16* __restrict__ VpT, u16* __restrict__ Opre) {
  __shared__ alignas(16) u16 klds[2][4096];     // [dc8][ks64][8], row-swizzled
  __shared__ alignas(16) u16 vlds[2][4096];     // [kc8][d64][8], row-swizzled
  __shared__ alignas(16) u16 plds[8][64 * 16];  // per-wave P^T [ks64][q16]

  const int tid = threadIdx.x;
  const int lane = tid & 63, wv = tid >> 6;   // 8 waves
  const int lr = lane & 15, lg = lane >> 4;
  const int q0 = blockIdx.y * 128;            // wave wv owns rows q0+wv*16..+15
  const int b = blockIdx.x >> 3, h = blockIdx.x & 7;
  const size_t rowbase = (size_t)b * SEQ;
  const int hoff = h * DH;

  // Q fragments for this wave's 16 q-rows, pre-scaled by 1/sqrt(512)*log2(e)
  const float csc = 0.063762f;
  short8 aq[2];
#pragma unroll
  for (int t = 0; t < 2; ++t) {
    short8 raw = *(const short8*)(Qp + (rowbase + q0 + wv * 16 + lr) * DIM +
                                  hoff + t * 32 + lg * 8);
    short8 s;
#pragma unroll
    for (int j = 0; j < 8; ++j) s[j] = (short)f2bf(bf2f((u16)raw[j]) * csc);
    aq[t] = s;
  }

  // all-ones bf16 B fragment for the row-sum MFMA
  short8 ones;
#pragma unroll
  for (int j = 0; j < 8; ++j) ones[j] = (short)0x3F80;

#define STAGEKV(buf, kt)                                                        \
  {                                                                             \
    const int ks0_ = (kt) * 64;                                                 \
    const int rr = tid & 63, cc = tid >> 6;                                     \
    const int srr = rr ^ (cc << 1);                                             \
    gload_lds16(Kp + (rowbase + ks0_ + srr) * DIM + hoff + cc * 8,              \
                &klds[buf][tid * 8]);                                           \
    gload_lds16(VpT + (size_t)b * (DIM * SEQ) + (size_t)(hoff + srr) * SEQ +    \
                    ks0_ + cc * 8,                                              \
                &vlds[buf][tid * 8]);                                           \
  }

  const int kx0 = lr ^ (lg << 1);

  u16* pw = &plds[wv][0];
  unsigned pbase = (unsigned)(uintptr_t)(__attribute__((address_space(3))) u16*)pw;
  const unsigned ta00 = pbase + (unsigned)lg * 128u;
  const unsigned ta01 = ta00 + 128u;
  const unsigned ta10 = ta00 + 1024u;
  const unsigned ta11 = ta00 + 1152u;

  f32x4 l_acc = {};
  f32x4 o_acc[4] = {};

  STAGEKV(0, 0);
  __syncthreads();

  int cur = 0;
#pragma unroll 1
  for (int kt = 0; kt < 16; ++kt) {
    if (kt < 15) STAGEKV(cur ^ 1, kt + 1);

    // ---- QK^T from LDS K (swizzled row read) ----
    f32x4 sa[4] = {};
    __builtin_amdgcn_s_setprio(1);
#pragma unroll
    for (int t = 0; t < 2; ++t) {
      const int kxt = kx0 ^ (t << 3);
#pragma unroll
      for (int f = 0; f < 4; ++f) {
        short8 bk_ = *(const short8*)(&klds[cur][((lg + 4 * t) * 64 + f * 16 + kxt) * 8]);
        sa[f] = __builtin_amdgcn_mfma_f32_16x16x32_bf16(aq[t], bk_, sa[f], 0, 0, 0);
      }
    }
    __builtin_amdgcn_s_setprio(0);

    // ---- V fragments issued early (swizzled row read) ----
    short8 bvf[8];
#pragma unroll
    for (int n = 0; n < 4; ++n)
#pragma unroll
      for (int t = 0; t < 2; ++t) {
        const int kxt = kx0 ^ (t << 3);
        bvf[n * 2 + t] = *(const short8*)(&vlds[cur][((lg + 4 * t) * 64 + n * 16 + kxt) * 8]);
      }

    // ---- p = 2^sa ; pack to P^T [ks64][16q] in per-wave LDS ----
#pragma unroll
    for (int f = 0; f < 4; ++f) {
      float p0 = EXP2(sa[f][0]);
      float p1 = EXP2(sa[f][1]);
      float p2 = EXP2(sa[f][2]);
      float p3 = EXP2(sa[f][3]);
      unsigned lo, hi;
      asm("v_cvt_pk_bf16_f32 %0, %1, %2" : "=v"(lo) : "v"(p0), "v"(p1));
      asm("v_cvt_pk_bf16_f32 %0, %1, %2" : "=v"(hi) : "v"(p2), "v"(p3));
      uint2v pk; pk.x = lo; pk.y = hi;
      *(uint2v*)&pw[(f * 16 + lr) * 16 + lg * 4] = pk;
    }

    // ---- wave-local fence, hardware transpose-read P as A-fragments ----
    asm volatile("s_waitcnt lgkmcnt(0)" ::: "memory");
    uint2v t00, t01, t10, t11;
    asm volatile("ds_read_b64_tr_b16 %0, %1" : "=v"(t00) : "v"(ta00));
    asm volatile("ds_read_b64_tr_b16 %0, %1" : "=v"(t01) : "v"(ta01));
    asm volatile("ds_read_b64_tr_b16 %0, %1" : "=v"(t10) : "v"(ta10));
    asm volatile("ds_read_b64_tr_b16 %0, %1" : "=v"(t11) : "v"(ta11));
    asm volatile("s_waitcnt lgkmcnt(0)" ::: "memory");
    __builtin_amdgcn_sched_barrier(0);

    short8 ap[2];
    {
      union { unsigned u[4]; short8 s; } u0, u1;
      u0.u[0] = t00.x; u0.u[1] = t00.y; u0.u[2] = t01.x; u0.u[3] = t01.y;
      u1.u[0] = t10.x; u1.u[1] = t10.y; u1.u[2] = t11.x; u1.u[3] = t11.y;
      ap[0] = u0.s; ap[1] = u1.s;
    }

    // ---- PV + row-sum (ones-MFMA) ----
    __builtin_amdgcn_s_setprio(1);
#pragma unroll
    for (int n = 0; n < 4; ++n)
#pragma unroll
      for (int t = 0; t < 2; ++t)
        o_acc[n] = __builtin_amdgcn_mfma_f32_16x16x32_bf16(ap[t], bvf[n * 2 + t], o_acc[n], 0, 0, 0);
    l_acc = __builtin_amdgcn_mfma_f32_16x16x32_bf16(ap[0], ones, l_acc, 0, 0, 0);
    l_acc = __builtin_amdgcn_mfma_f32_16x16x32_bf16(ap[1], ones, l_acc, 0, 0, 0);
    __builtin_amdgcn_s_setprio(0);

    __syncthreads();
    cur ^= 1;
  }
#undef STAGEKV

  // ---- epilogue: divide by row sum (already per-lane), add Q residual ----
  float inv[4];
#pragma unroll
  for (int r = 0; r < 4; ++r) inv[r] = 1.0f / l_acc[r];
#pragma unroll
  for (int n = 0; n < 4; ++n)
#pragma unroll
    for (int r = 0; r < 4; ++r) {
      const size_t row = rowbase + q0 + wv * 16 + lg * 4 + r;
      const int col = hoff + n * 16 + lr;
      const float ctx = o_acc[n][r] * inv[r];
      const float qv = bf2f(Qp[row * DIM + col]);
      Opre[row * DIM + col] = f2bf(qv + ctx);
    }
}

// ---------- FFN: out = Opre + relu(Opre @ Wo^T + bo), f32 output ----------
// 64-row blocks: grid (128,4) = 512 blocks -> ALL 256 CUs active.
__global__ __launch_bounds__(256, 4) void ffn_gemm(
    const u16* __restrict__ Opre, const u16* __restrict__ Wo_bf,
    const float* __restrict__ bo, float* __restrict__ out) {
  __shared__ alignas(16) u16 ldsA[2 * 2048];   // 2 x 4 KB: A 64x32 bf16
  __shared__ alignas(16) u16 ldsB[2 * 4096];   // 2 x 8 KB: B 128x32 bf16

  const int tid = threadIdx.x;
  const int m0 = blockIdx.x * 64;
  const int n0 = blockIdx.y * 128;

  const int lane = tid & 63;
  const int wv = tid >> 6;
  const int wr = wv >> 1, wc = wv & 1;
  const int lr = lane & 15, lg = lane >> 4;
  const int wbase = tid & 192;

#define FSTAGE(buf, kt)                                                         \
  {                                                                             \
    const int rr = tid & 63, cc = tid >> 6;                                     \
    gload_lds16(Opre + (size_t)(m0 + rr) * DIM + (kt) * 32 + cc * 8,            \
                ldsA + (buf) * 2048 + tid * 8);                                 \
    _Pragma("unroll")                                                           \
    for (int i = 0; i < 2; ++i) {                                               \
      const int T = i * 256 + tid;                                              \
      const int row = T & 127, kc = T >> 7;                                     \
      gload_lds16(Wo_bf + (size_t)(n0 + row) * DIM + (kt) * 32 + kc * 8,        \
                  ldsB + (buf) * 4096 + (i * 256 + wbase) * 8);                 \
    }                                                                           \
  }

  f32x4 acc[2][4] = {};

  FSTAGE(0, 0);
  __syncthreads();

  int cur = 0;
#pragma unroll 1
  for (int kt = 0; kt < 16; ++kt) {
    if (kt < 15) FSTAGE(cur ^ 1, kt + 1);
    short8 av[2], bw[4];
#pragma unroll
    for (int m = 0; m < 2; ++m)
      av[m] = *(const short8*)(ldsA + cur * 2048 + (lg * 64 + wr * 32 + m * 16 + lr) * 8);
#pragma unroll
    for (int n = 0; n < 4; ++n)
      bw[n] = *(const short8*)(ldsB + cur * 4096 + (lg * 128 + wc * 64 + n * 16 + lr) * 8);
#pragma unroll
    for (int m = 0; m < 2; ++m)
#pragma unroll
      for (int n = 0; n < 4; ++n)
        acc[m][n] = __builtin_amdgcn_mfma_f32_16x16x32_bf16(av[m], bw[n], acc[m][n], 0, 0, 0);
    __syncthreads();
    cur ^= 1;
  }
#undef FSTAGE

  float bn[4];
#pragma unroll
  for (int n = 0; n < 4; ++n) bn[n] = bo[n0 + wc * 64 + n * 16 + lr];

#pragma unroll
  for (int m = 0; m < 2; ++m)
#pragma unroll
    for (int n = 0; n < 4; ++n)
#pragma unroll
      for (int r = 0; r < 4; ++r) {
        const int row = m0 + wr * 32 + m * 16 + lg * 4 + r;
        const int col = n0 + wc * 64 + n * 16 + lr;
        const float v = acc[m][n][r] + bn[n];
        const float o = bf2f(Opre[(size_t)row * DIM + col]);
        out[(size_t)row * DIM + col] = o + fmaxf(v, 0.f);
      }
}

// ---------- launch ----------
extern "C" void kernel_launch(void* const* d_in, const int* in_sizes, int n_in,
                              void* d_out, int out_size, void* d_ws, size_t ws_size,
                              hipStream_t stream) {
  const float* Q  = (const float*)d_in[0];
  const float* K  = (const float*)d_in[1];
  const float* Wq = (const float*)d_in[2];
  const float* bq = (const float*)d_in[3];
  const float* Wk = (const float*)d_in[4];
  const float* bk = (const float*)d_in[5];
  const float* Wv = (const float*)d_in[6];
  const float* bv = (const float*)d_in[7];
  const float* Wo = (const float*)d_in[8];
  const float* bo = (const float*)d_in[9];

  char* ws = (char*)d_ws;
  const size_t SZ = (size_t)MROWS * DIM * sizeof(u16);       // 8 MiB per bf16 tensor
  const size_t WSZ = 4 * (size_t)(DIM * DIM) * sizeof(u16);  // 2 MiB weights
  u16* Wbf  = (u16*)(ws + 0);
  u16* Qp   = (u16*)(ws + WSZ);
  u16* Kp   = (u16*)((char*)Qp + SZ);
  u16* VpT  = (u16*)((char*)Kp + SZ);
  u16* Opre = (u16*)((char*)VpT + SZ);

  cvt_w<<<dim3(256, 4), 256, 0, stream>>>(Wq, Wk, Wv, Wo, Wbf);
  proj_gemm<<<dim3(64, 4, 3), 256, 0, stream>>>(Q, K, Wbf, bq, bk, bv, Qp, Kp, VpT);
  attn_kernel<<<dim3(64, 8), 512, 0, stream>>>(Qp, Kp, VpT, Opre);
  ffn_gemm<<<dim3(128, 4), 256, 0, stream>>>(Opre, Wbf + 3 * (DIM * DIM), bo, (float*)d_out);
}